// Round 8
// baseline (2379.942 us; speedup 1.0000x reference)
//
#include <hip/hip_runtime.h>
#include <hip/hip_fp16.h>

// DR2FWL2 conv, MI355X. mlp(e[idx]) == mlp(e)[idx] restructuring; MFMA bf16 hi/lo MLPs.
// R8: segment sums via LDS-AGGREGATED BUCKETS (no global atomics - the ~290G
// atomic-dword/s fabric ceiling that pinned seg3 at 131us x4). Preprocess once:
// bucket triangles by dst>>5 into per-class streams (hist -> scan -> 8B-payload
// scatter, ~28k contiguous streams so no R4-style write amplification). Hot segbkt:
// 1 wave/bucket, fp32 LDS accumulators, ds_add_f32 (fire-and-forget), one fused
// writeback: e += accE (classes A,C), mB = accM (class B; memsets deleted).

typedef unsigned short u16;
typedef unsigned int u32;
typedef unsigned long long u64;
typedef _Float16 f16;
typedef __attribute__((ext_vector_type(8))) short s16x8;
typedef __attribute__((ext_vector_type(4))) float f32x4;
typedef __attribute__((ext_vector_type(8))) _Float16 f16x8;

#define MFMA16(a, b, c) __builtin_amdgcn_mfma_f32_16x16x32_bf16((a), (b), (c), 0, 0, 0)

static __device__ __forceinline__ u16 bf16_rne(float x) {
  u32 u = __float_as_uint(x);
  return (u16)((u + 0x7fffu + ((u >> 16) & 1u)) >> 16);
}
static __device__ __forceinline__ float bf16_f32(u16 h) {
  return __uint_as_float(((u32)h) << 16);
}
static __device__ __forceinline__ void cvt_hilo8_f16(const f16x8 v, s16x8& hi, s16x8& lo) {
#pragma unroll
  for (int j = 0; j < 8; j++) {
    float x = (float)v[j];
    u16 h = bf16_rne(x);
    hi[j] = (short)h;
    lo[j] = (short)bf16_rne(x - bf16_f32(h));
  }
}

// ---- bucket build -----------------------------------------------------------
// class c -> (D = dst idx, A/B = gather idx), all length T (verified R5: both outputs pass)
static __device__ __forceinline__ void class_ptrs(int c, const int* t111, const int* t112,
                                                  const int* t122, const int* t222, int T,
                                                  const int*& D, const int*& A, const int*& B) {
  switch (c) {
    case 0: D = t111;          A = t111 + T; B = t111 + 2 * T; break;  // m111
    case 1: D = t112;          A = t112 + T; B = t112 + 2 * T; break;  // m112
    case 2: D = t122;          A = t122 + T; B = t122 + 2 * T; break;  // m122
    case 3: D = t112 + 2 * T;  A = t112;     B = t112 + T;     break;  // m211
    case 4: D = t122 + T;      A = t122;     B = t122 + 2 * T; break;  // m212
    default: D = t222;         A = t222 + T; B = t222 + 2 * T; break;  // m222
  }
}
static __device__ __forceinline__ int cls_ofs(int c, int NB1, int NB2) {
  return (c < 3) ? c * NB1 : 3 * NB1 + (c - 3) * NB2;
}

__global__ __launch_bounds__(256) void hist_kernel(int* __restrict__ cnt,
                                                   const int* t111, const int* t112,
                                                   const int* t122, const int* t222,
                                                   int T, int NB1, int NB2) {
  int i = blockIdx.x * 256 + threadIdx.x;
  if (i >= 6 * T) return;
  int c = i / T, t = i - c * T;
  const int *D, *A, *B;
  class_ptrs(c, t111, t112, t122, t222, T, D, A, B);
  atomicAdd(&cnt[cls_ofs(c, NB1, NB2) + (D[t] >> 5)], 1);
}

// single-WG chunked exclusive scan of cnt[0..CNT) -> boff (CNT+1) and pos (cursor copy)
__global__ __launch_bounds__(1024) void scan_kernel(const int* __restrict__ cnt, int* __restrict__ boff,
                                                    int* __restrict__ pos, int CNT) {
  __shared__ int sh[1024];
  __shared__ int carry;
  int tid = threadIdx.x;
  if (tid == 0) carry = 0;
  __syncthreads();
  for (int base0 = 0; base0 < CNT; base0 += 1024) {
    int i = base0 + tid;
    int v = (i < CNT) ? cnt[i] : 0;
    sh[tid] = v;
    __syncthreads();
    for (int off = 1; off < 1024; off <<= 1) {
      int x = (tid >= off) ? sh[tid - off] : 0;
      __syncthreads();
      sh[tid] += x;
      __syncthreads();
    }
    int incl = sh[tid];
    int cbase = carry;
    if (i < CNT) { boff[i] = cbase + incl - v; pos[i] = cbase + incl - v; }
    __syncthreads();
    if (tid == 1023) carry = cbase + incl;
    __syncthreads();
  }
  if (tid == 0) boff[CNT] = carry;
}

// payload = ia | ib<<20 | (dst&31)<<40  (valid for E < 2^20)
__global__ __launch_bounds__(256) void scatter_kernel(int* __restrict__ pos, u64* __restrict__ payload,
                                                      const int* t111, const int* t112,
                                                      const int* t122, const int* t222,
                                                      int T, int NB1, int NB2) {
  int i = blockIdx.x * 256 + threadIdx.x;
  if (i >= 6 * T) return;
  int c = i / T, t = i - c * T;
  const int *D, *A, *B;
  class_ptrs(c, t111, t112, t122, t222, T, D, A, B);
  int d = D[t];
  int slot = atomicAdd(&pos[cls_ofs(c, NB1, NB2) + (d >> 5)], 1);
  payload[slot] = (u64)(u32)A[t] | ((u64)(u32)B[t] << 20) | ((u64)(d & 31) << 40);
}

// ---- hot seg kernel: 1 wave per 32-row bucket, fp32 LDS accumulation --------
// e[rows] += sum(classA) + sum(classC);  mB[rows] = sum(classB)
__global__ __launch_bounds__(64) void segbkt_kernel(
    __half2* __restrict__ e, __half2* __restrict__ mB,
    const u64* __restrict__ payload, const int* __restrict__ boff,
    int ofsA, int ofsB, int ofsC,
    const __half2* __restrict__ paA, const __half2* __restrict__ pbA,
    const __half2* __restrict__ paB, const __half2* __restrict__ pbB,
    const __half2* __restrict__ paC, const __half2* __restrict__ pbC,
    int E) {
  __shared__ float accE[32 * 64];
  __shared__ float accM[32 * 64];
  const int b = blockIdx.x;
  const int tid = threadIdx.x;      // 0..63
  const int h = tid >> 5;           // triangle slot (2 per iteration)
  const int cl = tid & 31;          // channel-pair
#pragma unroll
  for (int i = 0; i < 32; i++) {
    accE[i * 64 + tid] = 0.0f;
    accM[i * 64 + tid] = 0.0f;
  }
  __syncthreads();

#pragma unroll
  for (int k = 0; k < 3; k++) {
    const int ofs = (k == 0) ? ofsA : (k == 1) ? ofsB : ofsC;
    const __half2* pa = (k == 0) ? paA : (k == 1) ? paB : paC;
    const __half2* pb = (k == 0) ? pbA : (k == 1) ? pbB : pbC;
    float* acc = (k == 1) ? accM : accE;
    const int t0 = boff[ofs + b], t1 = boff[ofs + b + 1];
    for (int t = t0 + h; t < t1; t += 2) {
      u64 p = payload[t];
      int ia = (int)(p & 0xFFFFF);
      int ib = (int)((p >> 20) & 0xFFFFF);
      int dlo = (int)(p >> 40);
      float2 a = __half22float2(pa[(size_t)ia * 32 + cl]);
      float2 v = __half22float2(pb[(size_t)ib * 32 + cl]);
      atomicAdd(&acc[dlo * 64 + 2 * cl], a.x * v.x);      // ds_add_f32, no return
      atomicAdd(&acc[dlo * 64 + 2 * cl + 1], a.y * v.y);
    }
  }
  __syncthreads();

  const int rbase = b * 32;
#pragma unroll
  for (int it = 0; it < 16; it++) {
    int idx = it * 64 + tid;          // 1024 = 32 rows x 32 cps
    int row = idx >> 5, cp = idx & 31;
    int grow = rbase + row;
    if (grow < E) {
      size_t g = (size_t)grow * 32 + cp;
      float2 ae = make_float2(accE[row * 64 + 2 * cp], accE[row * 64 + 2 * cp + 1]);
      float2 am = make_float2(accM[row * 64 + 2 * cp], accM[row * 64 + 2 * cp + 1]);
      float2 ev = __half22float2(e[g]);
      e[g] = __floats2half2_rn(ev.x + ae.x, ev.y + ae.y);
      mB[g] = __floats2half2_rn(am.x, am.y);
    }
  }
}

// ---- misc elementwise ---------------------------------------------------------
__global__ __launch_bounds__(256) void repack_split_kernel(const float* __restrict__ src,
                                                           u16* __restrict__ hi, u16* __restrict__ lo, int nmat) {
  int o = blockIdx.x * 256 + threadIdx.x;
  int stride = gridDim.x * 256;
  int total = nmat * 4096;
  for (; o < total; o += stride) {
    int m = o >> 12, r = o & 4095;
    int j = r & 7, lane = (r >> 3) & 63, nt = (r >> 9) & 3, kt = (r >> 11) & 1;
    int k = kt * 32 + ((lane >> 4) << 3) + j;
    int n = nt * 16 + (lane & 15);
    float x = src[(size_t)m * 4096 + k * 64 + n];
    u16 h = bf16_rne(x);
    hi[o] = h;
    lo[o] = bf16_rne(x - bf16_f32(h));
  }
}

__global__ __launch_bounds__(256) void cvtcopy_kernel(const float* __restrict__ src, f16* __restrict__ dst, int n8) {
  int i = blockIdx.x * 256 + threadIdx.x;
  int stride = gridDim.x * 256;
  const f32x4* s4 = (const f32x4*)src;
  f16x8* d8 = (f16x8*)dst;
  for (; i < n8; i += stride) {
    f32x4 a = s4[2 * i], b = s4[2 * i + 1];
    f16x8 o;
#pragma unroll
    for (int j = 0; j < 4; j++) { o[j] = (f16)a[j]; o[4 + j] = (f16)b[j]; }
    d8[i] = o;
  }
}

__global__ __launch_bounds__(256) void relu16_kernel(f16* __restrict__ e, int n8) {
  int i = blockIdx.x * 256 + threadIdx.x;
  int stride = gridDim.x * 256;
  f16x8* e8 = (f16x8*)e;
  for (; i < n8; i += stride) {
    f16x8 v = e8[i];
#pragma unroll
    for (int j = 0; j < 8; j++) v[j] = v[j] > (f16)0 ? v[j] : (f16)0;
    e8[i] = v;
  }
}

// e[r] += B[r] + B[inv[r]]  (+ optional relu); e,B fp16
template <bool DO_RELU>
__global__ __launch_bounds__(256) void addinvB_kernel(f16* __restrict__ e, const f16* __restrict__ B,
                                                      const int* __restrict__ inv, int E) {
  int i = blockIdx.x * 256 + threadIdx.x;
  int stride = gridDim.x * 256;
  int total = E * 8;
  f16x8* e8 = (f16x8*)e;
  const f16x8* B8 = (const f16x8*)B;
  for (; i < total; i += stride) {
    int r = i >> 3, q = i & 7;
    int ir = inv[r];
    f16x8 ev = e8[i];
    f16x8 bv = B8[i];
    f16x8 biv = B8[(size_t)ir * 8 + q];
#pragma unroll
    for (int j = 0; j < 8; j++) {
      float x = (float)ev[j] + (float)bv[j] + (float)biv[j];
      ev[j] = (f16)(DO_RELU ? fmaxf(x, 0.0f) : x);
    }
    e8[i] = ev;
  }
}

// ---- MLP / linear ---------------------------------------------------------------
__global__ __launch_bounds__(256) void mlpN_kernel(
    const f16* __restrict__ e1s, const f16* __restrict__ e2s,
    f16* __restrict__ d0, f16* __restrict__ d1, f16* __restrict__ d2,
    f16* __restrict__ d3, f16* __restrict__ d4, f16* __restrict__ d5,
    const u16* __restrict__ w1h_, const u16* __restrict__ w1l_,
    const u16* __restrict__ w2h_, const u16* __restrict__ w2l_,
    const float* __restrict__ b1_, const float* __restrict__ b2_,
    int miPacked, int selMask, int nUnits, int s1, int s2, int BPU) {
  __shared__ float hshm[4][1024];
  const int u = blockIdx.x / BPU;
  if (u >= nUnits) return;
  const int tid = threadIdx.x;
  const int wave = tid >> 6, lane = tid & 63;
  const int lrow = lane & 15, lk = lane >> 4;

  const int mi = (miPacked >> (4 * u)) & 15;
  const int sel = (selMask >> u) & 1;
  const f16* src = sel ? e2s : e1s;
  const int strips = sel ? s2 : s1;
  f16* dst = (u == 0) ? d0 : (u == 1) ? d1 : (u == 2) ? d2 : (u == 3) ? d3 : (u == 4) ? d4 : d5;

  const s16x8* W1H = (const s16x8*)(w1h_ + (size_t)mi * 4096);
  const s16x8* W1L = (const s16x8*)(w1l_ + (size_t)mi * 4096);
  const s16x8* W2H = (const s16x8*)(w2h_ + (size_t)mi * 4096);
  const s16x8* W2L = (const s16x8*)(w2l_ + (size_t)mi * 4096);
  s16x8 w1h[2][4], w1l[2][4], w2h[2][4], w2l[2][4];
#pragma unroll
  for (int kt = 0; kt < 2; kt++)
#pragma unroll
    for (int nt = 0; nt < 4; nt++) {
      const int f = (kt * 4 + nt) * 64 + lane;
      w1h[kt][nt] = W1H[f];
      w1l[kt][nt] = W1L[f];
      w2h[kt][nt] = W2H[f];
      w2l[kt][nt] = W2L[f];
    }
  float bias1[4], bias2[4];
#pragma unroll
  for (int nt = 0; nt < 4; nt++) {
    bias1[nt] = b1_[mi * 64 + nt * 16 + lrow];
    bias2[nt] = b2_[mi * 64 + nt * 16 + lrow];
  }

  float* hl = hshm[wave];
  const int lb = blockIdx.x % BPU;
  for (int strip = lb * 4 + wave; strip < strips; strip += BPU * 4) {
    const f16* xp = src + (size_t)(strip * 16 + lrow) * 64 + lk * 8;
    f16x8 xa = *(const f16x8*)(xp);
    f16x8 xb = *(const f16x8*)(xp + 32);
    s16x8 ah[2], al[2];
    cvt_hilo8_f16(xa, ah[0], al[0]);
    cvt_hilo8_f16(xb, ah[1], al[1]);

    f32x4 acc[4];
#pragma unroll
    for (int nt = 0; nt < 4; nt++) { acc[nt][0] = bias1[nt]; acc[nt][1] = bias1[nt]; acc[nt][2] = bias1[nt]; acc[nt][3] = bias1[nt]; }
#pragma unroll
    for (int kt = 0; kt < 2; kt++)
#pragma unroll
      for (int nt = 0; nt < 4; nt++) {
        acc[nt] = MFMA16(ah[kt], w1h[kt][nt], acc[nt]);
        acc[nt] = MFMA16(ah[kt], w1l[kt][nt], acc[nt]);
        acc[nt] = MFMA16(al[kt], w1h[kt][nt], acc[nt]);
      }

#pragma unroll
    for (int nt = 0; nt < 4; nt++)
#pragma unroll
      for (int r = 0; r < 4; r++) {
        const int row = lk * 4 + r;
        const int col = nt * 16 + lrow;
        hl[row * 64 + (col ^ ((row & 7) << 2))] = fmaxf(acc[nt][r], 0.0f);
      }
    s16x8 bh[2], bl[2];
#pragma unroll
    for (int kt = 0; kt < 2; kt++) {
      const int colb = kt * 32 + lk * 8;
      const int xr = (lrow & 7) << 2;
      f32x4 h0 = *(const f32x4*)&hl[lrow * 64 + ((colb + 0) ^ xr)];
      f32x4 h1 = *(const f32x4*)&hl[lrow * 64 + ((colb + 4) ^ xr)];
      s16x8 hi, lo;
#pragma unroll
      for (int j = 0; j < 4; j++) {
        float x = h0[j];
        u16 hh = bf16_rne(x);
        hi[j] = (short)hh; lo[j] = (short)bf16_rne(x - bf16_f32(hh));
      }
#pragma unroll
      for (int j = 0; j < 4; j++) {
        float x = h1[j];
        u16 hh = bf16_rne(x);
        hi[4 + j] = (short)hh; lo[4 + j] = (short)bf16_rne(x - bf16_f32(hh));
      }
      bh[kt] = hi; bl[kt] = lo;
    }

    f32x4 out[4];
#pragma unroll
    for (int nt = 0; nt < 4; nt++) { out[nt][0] = bias2[nt]; out[nt][1] = bias2[nt]; out[nt][2] = bias2[nt]; out[nt][3] = bias2[nt]; }
#pragma unroll
    for (int kt = 0; kt < 2; kt++)
#pragma unroll
      for (int nt = 0; nt < 4; nt++) {
        out[nt] = MFMA16(bh[kt], w2h[kt][nt], out[nt]);
        out[nt] = MFMA16(bh[kt], w2l[kt][nt], out[nt]);
        out[nt] = MFMA16(bl[kt], w2h[kt][nt], out[nt]);
      }

    f16* dp = dst + (size_t)strip * 1024;
#pragma unroll
    for (int nt = 0; nt < 4; nt++)
#pragma unroll
      for (int r = 0; r < 4; r++)
        dp[(lk * 4 + r) * 64 + nt * 16 + lrow] = (f16)out[nt][r];
  }
}

template <bool RELU>
__global__ __launch_bounds__(256) void lin_kernel(const f16* __restrict__ src, float* __restrict__ dst,
                                                  const u16* __restrict__ wh_, const u16* __restrict__ wl_,
                                                  const float* __restrict__ b_, int nstrips) {
  const int tid = threadIdx.x;
  const int wave = tid >> 6, lane = tid & 63;
  const int lrow = lane & 15, lk = lane >> 4;

  const s16x8* WH = (const s16x8*)wh_;
  const s16x8* WL = (const s16x8*)wl_;
  s16x8 wh[2][4], wl[2][4];
#pragma unroll
  for (int kt = 0; kt < 2; kt++)
#pragma unroll
    for (int nt = 0; nt < 4; nt++) {
      const int f = (kt * 4 + nt) * 64 + lane;
      wh[kt][nt] = WH[f];
      wl[kt][nt] = WL[f];
    }
  float bias[4];
#pragma unroll
  for (int nt = 0; nt < 4; nt++) bias[nt] = b_[nt * 16 + lrow];

  for (int s = blockIdx.x * 4 + wave; s < nstrips; s += gridDim.x * 4) {
    const f16* xp = src + (size_t)(s * 16 + lrow) * 64 + lk * 8;
    f16x8 xa = *(const f16x8*)(xp);
    f16x8 xb = *(const f16x8*)(xp + 32);
    if (RELU) {
#pragma unroll
      for (int j = 0; j < 8; j++) {
        xa[j] = xa[j] > (f16)0 ? xa[j] : (f16)0;
        xb[j] = xb[j] > (f16)0 ? xb[j] : (f16)0;
      }
    }
    s16x8 ah[2], al[2];
    cvt_hilo8_f16(xa, ah[0], al[0]);
    cvt_hilo8_f16(xb, ah[1], al[1]);

    f32x4 acc[4];
#pragma unroll
    for (int nt = 0; nt < 4; nt++) { acc[nt][0] = bias[nt]; acc[nt][1] = bias[nt]; acc[nt][2] = bias[nt]; acc[nt][3] = bias[nt]; }
#pragma unroll
    for (int kt = 0; kt < 2; kt++)
#pragma unroll
      for (int nt = 0; nt < 4; nt++) {
        acc[nt] = MFMA16(ah[kt], wh[kt][nt], acc[nt]);
        acc[nt] = MFMA16(ah[kt], wl[kt][nt], acc[nt]);
        acc[nt] = MFMA16(al[kt], wh[kt][nt], acc[nt]);
      }
    float* dp = dst + (size_t)s * 1024;
#pragma unroll
    for (int nt = 0; nt < 4; nt++)
#pragma unroll
      for (int r = 0; r < 4; r++)
        dp[(lk * 4 + r) * 64 + nt * 16 + lrow] = acc[nt][r];
  }
}

extern "C" void kernel_launch(void* const* d_in, const int* in_sizes, int n_in,
                              void* d_out, int out_size, void* d_ws, size_t ws_size,
                              hipStream_t stream) {
  const float* in_e1 = (const float*)d_in[0];
  const float* in_e2 = (const float*)d_in[1];
  const int* t111 = (const int*)d_in[2];
  const int* t112 = (const int*)d_in[3];
  const int* t122 = (const int*)d_in[4];
  const int* t222 = (const int*)d_in[5];
  const int* inv1 = (const int*)d_in[6];
  const int* inv2 = (const int*)d_in[7];
  const float* mw1 = (const float*)d_in[8];
  const float* mb1 = (const float*)d_in[9];
  const float* mw2 = (const float*)d_in[10];
  const float* mb2 = (const float*)d_in[11];
  const float* lw1 = (const float*)d_in[12];
  const float* lb1 = (const float*)d_in[13];
  const float* lw2 = (const float*)d_in[14];
  const float* lb2 = (const float*)d_in[15];

  const int E1 = in_sizes[0] / 64, E2 = in_sizes[1] / 64;
  const int T = in_sizes[2] / 3;
  const int L = in_sizes[8] / (8 * 64 * 64);
  const size_t nE1 = (size_t)E1 * 64, nE2 = (size_t)E2 * 64;
  const size_t nMax = nE1 > nE2 ? nE1 : nE2;
  const int NB1 = (E1 + 31) / 32, NB2 = (E2 + 31) / 32;
  const int CNT = 3 * NB1 + 3 * NB2;

  // ws: e1b,e2b,mB,q0,q1 fp16 | payload u64 | weights | cnt,boff,pos ints
  f16* e1b = (f16*)d_ws;
  f16* e2b = e1b + nE1;
  f16* mB = e2b + nE2;
  f16* q0 = mB + nMax;
  f16* q1 = q0 + nE1;
  u64* payload = (u64*)(q1 + nE1);          // 6*T (8B-aligned: all prior sizes even)
  const size_t wmat = (size_t)L * 8 * 4096;
  u16* w1h = (u16*)(payload + (size_t)6 * T);
  u16* w1l = w1h + wmat;
  u16* w2h = w1l + wmat;
  u16* w2l = w2h + wmat;
  u16* lwh = w2l + wmat;
  u16* lwl = lwh + 8192;
  int* cnt = (int*)(lwl + 8192);
  int* boff = cnt + CNT;                    // CNT+1
  int* pos = boff + CNT + 1;                // CNT
  const size_t needB = (char*)(pos + CNT) - (char*)d_ws + 64;
  if (ws_size < needB) return;

  // q2,q3,q6,q7 (fp16, E2-sized) live in d_out; dead before the lins write it
  f16* q2 = (f16*)d_out;
  f16* q3 = q2 + nE2;
  f16* q6 = q3 + nE2;
  f16* q7 = q6 + nE2;
  f16* q4 = q0;  // alias: q0/q1 dead after phase-1 seg
  f16* q5 = q1;

  const int s1 = E1 / 16, s2 = E2 / 16;
  const int ELTB = 2048, BPU = 256, LINB = 256;
  const int triB = (6 * T + 255) / 256;

  // ---- bucket build (once per launch; index arrays are fixed inputs) ----
  hipMemsetAsync(cnt, 0, (size_t)CNT * 4, stream);
  hist_kernel<<<triB, 256, 0, stream>>>(cnt, t111, t112, t122, t222, T, NB1, NB2);
  scan_kernel<<<1, 1024, 0, stream>>>(cnt, boff, pos, CNT);
  scatter_kernel<<<triB, 256, 0, stream>>>(pos, payload, t111, t112, t122, t222, T, NB1, NB2);

  // ---- weights & state ----
  repack_split_kernel<<<256, 256, 0, stream>>>(mw1, w1h, w1l, L * 8);
  repack_split_kernel<<<256, 256, 0, stream>>>(mw2, w2h, w2l, L * 8);
  repack_split_kernel<<<32, 256, 0, stream>>>(lw1, lwh, lwl, 1);
  repack_split_kernel<<<32, 256, 0, stream>>>(lw2, lwh + 4096, lwl + 4096, 1);
  cvtcopy_kernel<<<ELTB, 256, 0, stream>>>(in_e1, e1b, (int)(nE1 / 8));
  cvtcopy_kernel<<<ELTB, 256, 0, stream>>>(in_e2, e2b, (int)(nE2 / 8));

  for (int li = 0; li < L; li++) {
    const u16* W1H = w1h + (size_t)li * 8 * 4096;
    const u16* W1L = w1l + (size_t)li * 8 * 4096;
    const u16* W2H = w2h + (size_t)li * 8 * 4096;
    const u16* W2L = w2l + (size_t)li * 8 * 4096;
    const float* B1 = mb1 + (size_t)li * 8 * 64;
    const float* B2 = mb2 + (size_t)li * 8 * 64;

    // M6: q0=mlp0(e1) q1=mlp1(e1) q2=mlp2(e2) q3=mlp3(e2) q6=mlp6(e2) q7=mlp7(e2)
    mlpN_kernel<<<6 * BPU, 256, 0, stream>>>(e1b, e2b, q0, q1, q2, q3, q6, q7,
                                             W1H, W1L, W2H, W2L, B1, B2,
                                             0x763210, 0x3C, 6, s1, s2, BPU);
    // phase 1: A=m111(cls0, q0*q0)->e1, B=m112(cls1, q1*q2)->mB, C=m122(cls2, q3*q3)->e1
    segbkt_kernel<<<NB1, 64, 0, stream>>>(
        (__half2*)e1b, (__half2*)mB, payload, boff,
        0 * NB1, 1 * NB1, 2 * NB1,
        (const __half2*)q0, (const __half2*)q0,
        (const __half2*)q1, (const __half2*)q2,
        (const __half2*)q3, (const __half2*)q3, E1);
    addinvB_kernel<false><<<ELTB, 256, 0, stream>>>(e1b, mB, inv1, E1);

    // M2: q4=mlp4(e1_new) q5=mlp5(e1_new)  (e1 pre-relu, per reference)
    mlpN_kernel<<<2 * BPU, 256, 0, stream>>>(e1b, e2b, q4, q5, q2, q3, q6, q7,
                                             W1H, W1L, W2H, W2L, B1, B2,
                                             0x54, 0x0, 2, s1, s2, BPU);
    if (li < L - 1) relu16_kernel<<<ELTB, 256, 0, stream>>>(e1b, (int)(nE1 / 8));

    // phase 2: A=m211(cls3, q4*q4)->e2, B=m212(cls4, q5*q6)->mB, C=m222(cls5, q7*q7)->e2
    segbkt_kernel<<<NB2, 64, 0, stream>>>(
        (__half2*)e2b, (__half2*)mB, payload, boff,
        3 * NB1, 3 * NB1 + NB2, 3 * NB1 + 2 * NB2,
        (const __half2*)q4, (const __half2*)q4,
        (const __half2*)q5, (const __half2*)q6,
        (const __half2*)q7, (const __half2*)q7, E2);
    addinvB_kernel<true><<<ELTB, 256, 0, stream>>>(e2b, mB, inv2, E2);  // + relu(e2)
  }

  // final linears (e1b pre-relu: fuse relu into load; e2b already relu'd)
  lin_kernel<true><<<LINB, 256, 0, stream>>>(e1b, (float*)d_out, lwh, lwl, lb1, s1);
  lin_kernel<false><<<LINB, 256, 0, stream>>>(e2b, (float*)d_out + nE1, lwh + 4096, lwl + 4096, lb2, s2);
}

// Round 9
// 2237.734 us; speedup vs baseline: 1.0635x; 1.0635x over previous
//
#include <hip/hip_runtime.h>
#include <hip/hip_fp16.h>

// DR2FWL2 conv, MI355X. mlp(e[idx]) == mlp(e)[idx] restructuring; MFMA bf16 hi/lo MLPs.
// R9: R8's LDS-bucket seg was right algorithmically (no global atomics, WRITE 150->37MB)
// but launched at 1 wave/WG with 16KB LDS -> 10 waves/CU -> latency-starved (occ 20%,
// VALU 4%). Fix: 256 threads/bucket (8 triangle slots), same 16KB LDS -> 8 WG/CU x
// 4 waves = 32 waves/CU (100% occ), 4x memory-level parallelism. Everything else as R8.

typedef unsigned short u16;
typedef unsigned int u32;
typedef unsigned long long u64;
typedef _Float16 f16;
typedef __attribute__((ext_vector_type(8))) short s16x8;
typedef __attribute__((ext_vector_type(4))) float f32x4;
typedef __attribute__((ext_vector_type(8))) _Float16 f16x8;

#define MFMA16(a, b, c) __builtin_amdgcn_mfma_f32_16x16x32_bf16((a), (b), (c), 0, 0, 0)

static __device__ __forceinline__ u16 bf16_rne(float x) {
  u32 u = __float_as_uint(x);
  return (u16)((u + 0x7fffu + ((u >> 16) & 1u)) >> 16);
}
static __device__ __forceinline__ float bf16_f32(u16 h) {
  return __uint_as_float(((u32)h) << 16);
}
static __device__ __forceinline__ void cvt_hilo8_f16(const f16x8 v, s16x8& hi, s16x8& lo) {
#pragma unroll
  for (int j = 0; j < 8; j++) {
    float x = (float)v[j];
    u16 h = bf16_rne(x);
    hi[j] = (short)h;
    lo[j] = (short)bf16_rne(x - bf16_f32(h));
  }
}

// ---- bucket build -----------------------------------------------------------
static __device__ __forceinline__ void class_ptrs(int c, const int* t111, const int* t112,
                                                  const int* t122, const int* t222, int T,
                                                  const int*& D, const int*& A, const int*& B) {
  switch (c) {
    case 0: D = t111;          A = t111 + T; B = t111 + 2 * T; break;  // m111
    case 1: D = t112;          A = t112 + T; B = t112 + 2 * T; break;  // m112
    case 2: D = t122;          A = t122 + T; B = t122 + 2 * T; break;  // m122
    case 3: D = t112 + 2 * T;  A = t112;     B = t112 + T;     break;  // m211
    case 4: D = t122 + T;      A = t122;     B = t122 + 2 * T; break;  // m212
    default: D = t222;         A = t222 + T; B = t222 + 2 * T; break;  // m222
  }
}
static __device__ __forceinline__ int cls_ofs(int c, int NB1, int NB2) {
  return (c < 3) ? c * NB1 : 3 * NB1 + (c - 3) * NB2;
}

__global__ __launch_bounds__(256) void hist_kernel(int* __restrict__ cnt,
                                                   const int* t111, const int* t112,
                                                   const int* t122, const int* t222,
                                                   int T, int NB1, int NB2) {
  int i = blockIdx.x * 256 + threadIdx.x;
  if (i >= 6 * T) return;
  int c = i / T, t = i - c * T;
  const int *D, *A, *B;
  class_ptrs(c, t111, t112, t122, t222, T, D, A, B);
  atomicAdd(&cnt[cls_ofs(c, NB1, NB2) + (D[t] >> 5)], 1);
}

__global__ __launch_bounds__(1024) void scan_kernel(const int* __restrict__ cnt, int* __restrict__ boff,
                                                    int* __restrict__ pos, int CNT) {
  __shared__ int sh[1024];
  __shared__ int carry;
  int tid = threadIdx.x;
  if (tid == 0) carry = 0;
  __syncthreads();
  for (int base0 = 0; base0 < CNT; base0 += 1024) {
    int i = base0 + tid;
    int v = (i < CNT) ? cnt[i] : 0;
    sh[tid] = v;
    __syncthreads();
    for (int off = 1; off < 1024; off <<= 1) {
      int x = (tid >= off) ? sh[tid - off] : 0;
      __syncthreads();
      sh[tid] += x;
      __syncthreads();
    }
    int incl = sh[tid];
    int cbase = carry;
    if (i < CNT) { boff[i] = cbase + incl - v; pos[i] = cbase + incl - v; }
    __syncthreads();
    if (tid == 1023) carry = cbase + incl;
    __syncthreads();
  }
  if (tid == 0) boff[CNT] = carry;
}

// payload = ia | ib<<20 | (dst&31)<<40  (valid for E < 2^20)
__global__ __launch_bounds__(256) void scatter_kernel(int* __restrict__ pos, u64* __restrict__ payload,
                                                      const int* t111, const int* t112,
                                                      const int* t122, const int* t222,
                                                      int T, int NB1, int NB2) {
  int i = blockIdx.x * 256 + threadIdx.x;
  if (i >= 6 * T) return;
  int c = i / T, t = i - c * T;
  const int *D, *A, *B;
  class_ptrs(c, t111, t112, t122, t222, T, D, A, B);
  int d = D[t];
  int slot = atomicAdd(&pos[cls_ofs(c, NB1, NB2) + (d >> 5)], 1);
  payload[slot] = (u64)(u32)A[t] | ((u64)(u32)B[t] << 20) | ((u64)(d & 31) << 40);
}

// ---- hot seg kernel: 256 threads (8 triangle slots) per 32-row bucket -------
// e[rows] += sum(classA) + sum(classC);  mB[rows] = sum(classB)
__global__ __launch_bounds__(256) void segbkt_kernel(
    __half2* __restrict__ e, __half2* __restrict__ mB,
    const u64* __restrict__ payload, const int* __restrict__ boff,
    int ofsA, int ofsB, int ofsC,
    const __half2* __restrict__ paA, const __half2* __restrict__ pbA,
    const __half2* __restrict__ paB, const __half2* __restrict__ pbB,
    const __half2* __restrict__ paC, const __half2* __restrict__ pbC,
    int E) {
  __shared__ float accE[32 * 64];
  __shared__ float accM[32 * 64];
  const int b = blockIdx.x;
  const int tid = threadIdx.x;      // 0..255
  const int h = tid >> 5;           // triangle slot 0..7
  const int cl = tid & 31;          // channel-pair
#pragma unroll
  for (int i = 0; i < 8; i++) {
    accE[i * 256 + tid] = 0.0f;
    accM[i * 256 + tid] = 0.0f;
  }
  __syncthreads();

#pragma unroll
  for (int k = 0; k < 3; k++) {
    const int ofs = (k == 0) ? ofsA : (k == 1) ? ofsB : ofsC;
    const __half2* pa = (k == 0) ? paA : (k == 1) ? paB : paC;
    const __half2* pb = (k == 0) ? pbA : (k == 1) ? pbB : pbC;
    float* acc = (k == 1) ? accM : accE;
    const int t0 = boff[ofs + b], t1 = boff[ofs + b + 1];
    for (int t = t0 + h; t < t1; t += 8) {
      u64 p = payload[t];
      int ia = (int)(p & 0xFFFFF);
      int ib = (int)((p >> 20) & 0xFFFFF);
      int dlo = (int)(p >> 40);
      float2 a = __half22float2(pa[(size_t)ia * 32 + cl]);
      float2 v = __half22float2(pb[(size_t)ib * 32 + cl]);
      atomicAdd(&acc[dlo * 64 + 2 * cl], a.x * v.x);      // ds_add_f32
      atomicAdd(&acc[dlo * 64 + 2 * cl + 1], a.y * v.y);
    }
  }
  __syncthreads();

  const int rbase = b * 32;
#pragma unroll
  for (int it = 0; it < 4; it++) {
    int idx = it * 256 + tid;         // 1024 = 32 rows x 32 cps
    int row = idx >> 5, cp = idx & 31;
    int grow = rbase + row;
    if (grow < E) {
      size_t g = (size_t)grow * 32 + cp;
      float2 ae = make_float2(accE[row * 64 + 2 * cp], accE[row * 64 + 2 * cp + 1]);
      float2 am = make_float2(accM[row * 64 + 2 * cp], accM[row * 64 + 2 * cp + 1]);
      float2 ev = __half22float2(e[g]);
      e[g] = __floats2half2_rn(ev.x + ae.x, ev.y + ae.y);
      mB[g] = __floats2half2_rn(am.x, am.y);
    }
  }
}

// ---- misc elementwise ---------------------------------------------------------
__global__ __launch_bounds__(256) void repack_split_kernel(const float* __restrict__ src,
                                                           u16* __restrict__ hi, u16* __restrict__ lo, int nmat) {
  int o = blockIdx.x * 256 + threadIdx.x;
  int stride = gridDim.x * 256;
  int total = nmat * 4096;
  for (; o < total; o += stride) {
    int m = o >> 12, r = o & 4095;
    int j = r & 7, lane = (r >> 3) & 63, nt = (r >> 9) & 3, kt = (r >> 11) & 1;
    int k = kt * 32 + ((lane >> 4) << 3) + j;
    int n = nt * 16 + (lane & 15);
    float x = src[(size_t)m * 4096 + k * 64 + n];
    u16 h = bf16_rne(x);
    hi[o] = h;
    lo[o] = bf16_rne(x - bf16_f32(h));
  }
}

__global__ __launch_bounds__(256) void cvtcopy_kernel(const float* __restrict__ src, f16* __restrict__ dst, int n8) {
  int i = blockIdx.x * 256 + threadIdx.x;
  int stride = gridDim.x * 256;
  const f32x4* s4 = (const f32x4*)src;
  f16x8* d8 = (f16x8*)dst;
  for (; i < n8; i += stride) {
    f32x4 a = s4[2 * i], b = s4[2 * i + 1];
    f16x8 o;
#pragma unroll
    for (int j = 0; j < 4; j++) { o[j] = (f16)a[j]; o[4 + j] = (f16)b[j]; }
    d8[i] = o;
  }
}

__global__ __launch_bounds__(256) void relu16_kernel(f16* __restrict__ e, int n8) {
  int i = blockIdx.x * 256 + threadIdx.x;
  int stride = gridDim.x * 256;
  f16x8* e8 = (f16x8*)e;
  for (; i < n8; i += stride) {
    f16x8 v = e8[i];
#pragma unroll
    for (int j = 0; j < 8; j++) v[j] = v[j] > (f16)0 ? v[j] : (f16)0;
    e8[i] = v;
  }
}

// e[r] += B[r] + B[inv[r]]  (+ optional relu); e,B fp16
template <bool DO_RELU>
__global__ __launch_bounds__(256) void addinvB_kernel(f16* __restrict__ e, const f16* __restrict__ B,
                                                      const int* __restrict__ inv, int E) {
  int i = blockIdx.x * 256 + threadIdx.x;
  int stride = gridDim.x * 256;
  int total = E * 8;
  f16x8* e8 = (f16x8*)e;
  const f16x8* B8 = (const f16x8*)B;
  for (; i < total; i += stride) {
    int r = i >> 3, q = i & 7;
    int ir = inv[r];
    f16x8 ev = e8[i];
    f16x8 bv = B8[i];
    f16x8 biv = B8[(size_t)ir * 8 + q];
#pragma unroll
    for (int j = 0; j < 8; j++) {
      float x = (float)ev[j] + (float)bv[j] + (float)biv[j];
      ev[j] = (f16)(DO_RELU ? fmaxf(x, 0.0f) : x);
    }
    e8[i] = ev;
  }
}

// ---- MLP / linear ---------------------------------------------------------------
__global__ __launch_bounds__(256) void mlpN_kernel(
    const f16* __restrict__ e1s, const f16* __restrict__ e2s,
    f16* __restrict__ d0, f16* __restrict__ d1, f16* __restrict__ d2,
    f16* __restrict__ d3, f16* __restrict__ d4, f16* __restrict__ d5,
    const u16* __restrict__ w1h_, const u16* __restrict__ w1l_,
    const u16* __restrict__ w2h_, const u16* __restrict__ w2l_,
    const float* __restrict__ b1_, const float* __restrict__ b2_,
    int miPacked, int selMask, int nUnits, int s1, int s2, int BPU) {
  __shared__ float hshm[4][1024];
  const int u = blockIdx.x / BPU;
  if (u >= nUnits) return;
  const int tid = threadIdx.x;
  const int wave = tid >> 6, lane = tid & 63;
  const int lrow = lane & 15, lk = lane >> 4;

  const int mi = (miPacked >> (4 * u)) & 15;
  const int sel = (selMask >> u) & 1;
  const f16* src = sel ? e2s : e1s;
  const int strips = sel ? s2 : s1;
  f16* dst = (u == 0) ? d0 : (u == 1) ? d1 : (u == 2) ? d2 : (u == 3) ? d3 : (u == 4) ? d4 : d5;

  const s16x8* W1H = (const s16x8*)(w1h_ + (size_t)mi * 4096);
  const s16x8* W1L = (const s16x8*)(w1l_ + (size_t)mi * 4096);
  const s16x8* W2H = (const s16x8*)(w2h_ + (size_t)mi * 4096);
  const s16x8* W2L = (const s16x8*)(w2l_ + (size_t)mi * 4096);
  s16x8 w1h[2][4], w1l[2][4], w2h[2][4], w2l[2][4];
#pragma unroll
  for (int kt = 0; kt < 2; kt++)
#pragma unroll
    for (int nt = 0; nt < 4; nt++) {
      const int f = (kt * 4 + nt) * 64 + lane;
      w1h[kt][nt] = W1H[f];
      w1l[kt][nt] = W1L[f];
      w2h[kt][nt] = W2H[f];
      w2l[kt][nt] = W2L[f];
    }
  float bias1[4], bias2[4];
#pragma unroll
  for (int nt = 0; nt < 4; nt++) {
    bias1[nt] = b1_[mi * 64 + nt * 16 + lrow];
    bias2[nt] = b2_[mi * 64 + nt * 16 + lrow];
  }

  float* hl = hshm[wave];
  const int lb = blockIdx.x % BPU;
  for (int strip = lb * 4 + wave; strip < strips; strip += BPU * 4) {
    const f16* xp = src + (size_t)(strip * 16 + lrow) * 64 + lk * 8;
    f16x8 xa = *(const f16x8*)(xp);
    f16x8 xb = *(const f16x8*)(xp + 32);
    s16x8 ah[2], al[2];
    cvt_hilo8_f16(xa, ah[0], al[0]);
    cvt_hilo8_f16(xb, ah[1], al[1]);

    f32x4 acc[4];
#pragma unroll
    for (int nt = 0; nt < 4; nt++) { acc[nt][0] = bias1[nt]; acc[nt][1] = bias1[nt]; acc[nt][2] = bias1[nt]; acc[nt][3] = bias1[nt]; }
#pragma unroll
    for (int kt = 0; kt < 2; kt++)
#pragma unroll
      for (int nt = 0; nt < 4; nt++) {
        acc[nt] = MFMA16(ah[kt], w1h[kt][nt], acc[nt]);
        acc[nt] = MFMA16(ah[kt], w1l[kt][nt], acc[nt]);
        acc[nt] = MFMA16(al[kt], w1h[kt][nt], acc[nt]);
      }

#pragma unroll
    for (int nt = 0; nt < 4; nt++)
#pragma unroll
      for (int r = 0; r < 4; r++) {
        const int row = lk * 4 + r;
        const int col = nt * 16 + lrow;
        hl[row * 64 + (col ^ ((row & 7) << 2))] = fmaxf(acc[nt][r], 0.0f);
      }
    s16x8 bh[2], bl[2];
#pragma unroll
    for (int kt = 0; kt < 2; kt++) {
      const int colb = kt * 32 + lk * 8;
      const int xr = (lrow & 7) << 2;
      f32x4 h0 = *(const f32x4*)&hl[lrow * 64 + ((colb + 0) ^ xr)];
      f32x4 h1 = *(const f32x4*)&hl[lrow * 64 + ((colb + 4) ^ xr)];
      s16x8 hi, lo;
#pragma unroll
      for (int j = 0; j < 4; j++) {
        float x = h0[j];
        u16 hh = bf16_rne(x);
        hi[j] = (short)hh; lo[j] = (short)bf16_rne(x - bf16_f32(hh));
      }
#pragma unroll
      for (int j = 0; j < 4; j++) {
        float x = h1[j];
        u16 hh = bf16_rne(x);
        hi[4 + j] = (short)hh; lo[4 + j] = (short)bf16_rne(x - bf16_f32(hh));
      }
      bh[kt] = hi; bl[kt] = lo;
    }

    f32x4 out[4];
#pragma unroll
    for (int nt = 0; nt < 4; nt++) { out[nt][0] = bias2[nt]; out[nt][1] = bias2[nt]; out[nt][2] = bias2[nt]; out[nt][3] = bias2[nt]; }
#pragma unroll
    for (int kt = 0; kt < 2; kt++)
#pragma unroll
      for (int nt = 0; nt < 4; nt++) {
        out[nt] = MFMA16(bh[kt], w2h[kt][nt], out[nt]);
        out[nt] = MFMA16(bh[kt], w2l[kt][nt], out[nt]);
        out[nt] = MFMA16(bl[kt], w2h[kt][nt], out[nt]);
      }

    f16* dp = dst + (size_t)strip * 1024;
#pragma unroll
    for (int nt = 0; nt < 4; nt++)
#pragma unroll
      for (int r = 0; r < 4; r++)
        dp[(lk * 4 + r) * 64 + nt * 16 + lrow] = (f16)out[nt][r];
  }
}

template <bool RELU>
__global__ __launch_bounds__(256) void lin_kernel(const f16* __restrict__ src, float* __restrict__ dst,
                                                  const u16* __restrict__ wh_, const u16* __restrict__ wl_,
                                                  const float* __restrict__ b_, int nstrips) {
  const int tid = threadIdx.x;
  const int wave = tid >> 6, lane = tid & 63;
  const int lrow = lane & 15, lk = lane >> 4;

  const s16x8* WH = (const s16x8*)wh_;
  const s16x8* WL = (const s16x8*)wl_;
  s16x8 wh[2][4], wl[2][4];
#pragma unroll
  for (int kt = 0; kt < 2; kt++)
#pragma unroll
    for (int nt = 0; nt < 4; nt++) {
      const int f = (kt * 4 + nt) * 64 + lane;
      wh[kt][nt] = WH[f];
      wl[kt][nt] = WL[f];
    }
  float bias[4];
#pragma unroll
  for (int nt = 0; nt < 4; nt++) bias[nt] = b_[nt * 16 + lrow];

  for (int s = blockIdx.x * 4 + wave; s < nstrips; s += gridDim.x * 4) {
    const f16* xp = src + (size_t)(s * 16 + lrow) * 64 + lk * 8;
    f16x8 xa = *(const f16x8*)(xp);
    f16x8 xb = *(const f16x8*)(xp + 32);
    if (RELU) {
#pragma unroll
      for (int j = 0; j < 8; j++) {
        xa[j] = xa[j] > (f16)0 ? xa[j] : (f16)0;
        xb[j] = xb[j] > (f16)0 ? xb[j] : (f16)0;
      }
    }
    s16x8 ah[2], al[2];
    cvt_hilo8_f16(xa, ah[0], al[0]);
    cvt_hilo8_f16(xb, ah[1], al[1]);

    f32x4 acc[4];
#pragma unroll
    for (int nt = 0; nt < 4; nt++) { acc[nt][0] = bias[nt]; acc[nt][1] = bias[nt]; acc[nt][2] = bias[nt]; acc[nt][3] = bias[nt]; }
#pragma unroll
    for (int kt = 0; kt < 2; kt++)
#pragma unroll
      for (int nt = 0; nt < 4; nt++) {
        acc[nt] = MFMA16(ah[kt], wh[kt][nt], acc[nt]);
        acc[nt] = MFMA16(ah[kt], wl[kt][nt], acc[nt]);
        acc[nt] = MFMA16(al[kt], wh[kt][nt], acc[nt]);
      }
    float* dp = dst + (size_t)s * 1024;
#pragma unroll
    for (int nt = 0; nt < 4; nt++)
#pragma unroll
      for (int r = 0; r < 4; r++)
        dp[(lk * 4 + r) * 64 + nt * 16 + lrow] = acc[nt][r];
  }
}

extern "C" void kernel_launch(void* const* d_in, const int* in_sizes, int n_in,
                              void* d_out, int out_size, void* d_ws, size_t ws_size,
                              hipStream_t stream) {
  const float* in_e1 = (const float*)d_in[0];
  const float* in_e2 = (const float*)d_in[1];
  const int* t111 = (const int*)d_in[2];
  const int* t112 = (const int*)d_in[3];
  const int* t122 = (const int*)d_in[4];
  const int* t222 = (const int*)d_in[5];
  const int* inv1 = (const int*)d_in[6];
  const int* inv2 = (const int*)d_in[7];
  const float* mw1 = (const float*)d_in[8];
  const float* mb1 = (const float*)d_in[9];
  const float* mw2 = (const float*)d_in[10];
  const float* mb2 = (const float*)d_in[11];
  const float* lw1 = (const float*)d_in[12];
  const float* lb1 = (const float*)d_in[13];
  const float* lw2 = (const float*)d_in[14];
  const float* lb2 = (const float*)d_in[15];

  const int E1 = in_sizes[0] / 64, E2 = in_sizes[1] / 64;
  const int T = in_sizes[2] / 3;
  const int L = in_sizes[8] / (8 * 64 * 64);
  const size_t nE1 = (size_t)E1 * 64, nE2 = (size_t)E2 * 64;
  const size_t nMax = nE1 > nE2 ? nE1 : nE2;
  const int NB1 = (E1 + 31) / 32, NB2 = (E2 + 31) / 32;
  const int CNT = 3 * NB1 + 3 * NB2;

  // ws: e1b,e2b,mB,q0,q1 fp16 | payload u64 | weights | cnt,boff,pos ints
  f16* e1b = (f16*)d_ws;
  f16* e2b = e1b + nE1;
  f16* mB = e2b + nE2;
  f16* q0 = mB + nMax;
  f16* q1 = q0 + nE1;
  u64* payload = (u64*)(q1 + nE1);          // 6*T
  const size_t wmat = (size_t)L * 8 * 4096;
  u16* w1h = (u16*)(payload + (size_t)6 * T);
  u16* w1l = w1h + wmat;
  u16* w2h = w1l + wmat;
  u16* w2l = w2h + wmat;
  u16* lwh = w2l + wmat;
  u16* lwl = lwh + 8192;
  int* cnt = (int*)(lwl + 8192);
  int* boff = cnt + CNT;                    // CNT+1
  int* pos = boff + CNT + 1;                // CNT
  const size_t needB = (char*)(pos + CNT) - (char*)d_ws + 64;
  if (ws_size < needB) return;

  // q2,q3,q6,q7 (fp16, E2-sized) live in d_out; dead before the lins write it
  f16* q2 = (f16*)d_out;
  f16* q3 = q2 + nE2;
  f16* q6 = q3 + nE2;
  f16* q7 = q6 + nE2;
  f16* q4 = q0;  // alias: q0/q1 dead after phase-1 seg
  f16* q5 = q1;

  const int s1 = E1 / 16, s2 = E2 / 16;
  const int ELTB = 2048, BPU = 256, LINB = 256;
  const int triB = (6 * T + 255) / 256;

  // ---- bucket build (once per launch; index arrays are fixed inputs) ----
  hipMemsetAsync(cnt, 0, (size_t)CNT * 4, stream);
  hist_kernel<<<triB, 256, 0, stream>>>(cnt, t111, t112, t122, t222, T, NB1, NB2);
  scan_kernel<<<1, 1024, 0, stream>>>(cnt, boff, pos, CNT);
  scatter_kernel<<<triB, 256, 0, stream>>>(pos, payload, t111, t112, t122, t222, T, NB1, NB2);

  // ---- weights & state ----
  repack_split_kernel<<<256, 256, 0, stream>>>(mw1, w1h, w1l, L * 8);
  repack_split_kernel<<<256, 256, 0, stream>>>(mw2, w2h, w2l, L * 8);
  repack_split_kernel<<<32, 256, 0, stream>>>(lw1, lwh, lwl, 1);
  repack_split_kernel<<<32, 256, 0, stream>>>(lw2, lwh + 4096, lwl + 4096, 1);
  cvtcopy_kernel<<<ELTB, 256, 0, stream>>>(in_e1, e1b, (int)(nE1 / 8));
  cvtcopy_kernel<<<ELTB, 256, 0, stream>>>(in_e2, e2b, (int)(nE2 / 8));

  for (int li = 0; li < L; li++) {
    const u16* W1H = w1h + (size_t)li * 8 * 4096;
    const u16* W1L = w1l + (size_t)li * 8 * 4096;
    const u16* W2H = w2h + (size_t)li * 8 * 4096;
    const u16* W2L = w2l + (size_t)li * 8 * 4096;
    const float* B1 = mb1 + (size_t)li * 8 * 64;
    const float* B2 = mb2 + (size_t)li * 8 * 64;

    // M6: q0=mlp0(e1) q1=mlp1(e1) q2=mlp2(e2) q3=mlp3(e2) q6=mlp6(e2) q7=mlp7(e2)
    mlpN_kernel<<<6 * BPU, 256, 0, stream>>>(e1b, e2b, q0, q1, q2, q3, q6, q7,
                                             W1H, W1L, W2H, W2L, B1, B2,
                                             0x763210, 0x3C, 6, s1, s2, BPU);
    // phase 1: A=m111(cls0, q0*q0)->e1, B=m112(cls1, q1*q2)->mB, C=m122(cls2, q3*q3)->e1
    segbkt_kernel<<<NB1, 256, 0, stream>>>(
        (__half2*)e1b, (__half2*)mB, payload, boff,
        0 * NB1, 1 * NB1, 2 * NB1,
        (const __half2*)q0, (const __half2*)q0,
        (const __half2*)q1, (const __half2*)q2,
        (const __half2*)q3, (const __half2*)q3, E1);
    addinvB_kernel<false><<<ELTB, 256, 0, stream>>>(e1b, mB, inv1, E1);

    // M2: q4=mlp4(e1_new) q5=mlp5(e1_new)  (e1 pre-relu, per reference)
    mlpN_kernel<<<2 * BPU, 256, 0, stream>>>(e1b, e2b, q4, q5, q2, q3, q6, q7,
                                             W1H, W1L, W2H, W2L, B1, B2,
                                             0x54, 0x0, 2, s1, s2, BPU);
    if (li < L - 1) relu16_kernel<<<ELTB, 256, 0, stream>>>(e1b, (int)(nE1 / 8));

    // phase 2: A=m211(cls3, q4*q4)->e2, B=m212(cls4, q5*q6)->mB, C=m222(cls5, q7*q7)->e2
    segbkt_kernel<<<NB2, 256, 0, stream>>>(
        (__half2*)e2b, (__half2*)mB, payload, boff,
        3 * NB1, 3 * NB1 + NB2, 3 * NB1 + 2 * NB2,
        (const __half2*)q4, (const __half2*)q4,
        (const __half2*)q5, (const __half2*)q6,
        (const __half2*)q7, (const __half2*)q7, E2);
    addinvB_kernel<true><<<ELTB, 256, 0, stream>>>(e2b, mB, inv2, E2);  // + relu(e2)
  }

  // final linears (e1b pre-relu: fuse relu into load; e2b already relu'd)
  lin_kernel<true><<<LINB, 256, 0, stream>>>(e1b, (float*)d_out, lwh, lwl, lb1, s1);
  lin_kernel<false><<<LINB, 256, 0, stream>>>(e2b, (float*)d_out + nE1, lwh + 4096, lwl + 4096, lb2, s2);
}

// Round 10
// 807.863 us; speedup vs baseline: 2.9460x; 2.7699x over previous
//
#include <hip/hip_runtime.h>
#include <hip/hip_fp16.h>

// DR2FWL2 conv, MI355X. mlp(e[idx]) == mlp(e)[idx] restructuring; MFMA bf16 hi/lo MLPs.
// R10: revert seg to R7's triangle-push packed-fp16 atomics (proven 131us/phase, jointly
// at the ~293G atomic-dword/s AND ~2.3TB/s random-gather ceilings; pull variants: CSR
// 112+build, bucket 413 - both net-worse). Consolidation: 1 repack dispatch (was 4,
// unified weight array), 1 cvtcopy (was 2), 1 fused lin dispatch (was 2).

typedef unsigned short u16;
typedef unsigned int u32;
typedef _Float16 f16;
typedef __attribute__((ext_vector_type(8))) short s16x8;
typedef __attribute__((ext_vector_type(4))) float f32x4;
typedef __attribute__((ext_vector_type(8))) _Float16 f16x8;

#define MFMA16(a, b, c) __builtin_amdgcn_mfma_f32_16x16x32_bf16((a), (b), (c), 0, 0, 0)

static __device__ __forceinline__ u16 bf16_rne(float x) {
  u32 u = __float_as_uint(x);
  return (u16)((u + 0x7fffu + ((u >> 16) & 1u)) >> 16);
}
static __device__ __forceinline__ float bf16_f32(u16 h) {
  return __uint_as_float(((u32)h) << 16);
}
static __device__ __forceinline__ void cvt_hilo8_f16(const f16x8 v, s16x8& hi, s16x8& lo) {
#pragma unroll
  for (int j = 0; j < 8; j++) {
    float x = (float)v[j];
    u16 h = bf16_rne(x);
    hi[j] = (short)h;
    lo[j] = (short)bf16_rne(x - bf16_f32(h));
  }
}

// Unified repack: all [64][64] weight matrices -> fragment-ordered bf16 hi/lo in ONE
// array. Layout: [L*8 mlp-W1 | L*8 mlp-W2 | lin1 | lin2], matrix m at hi/lo + m*4096.
__global__ __launch_bounds__(256) void repack_all_kernel(const float* __restrict__ mw1,
                                                         const float* __restrict__ mw2,
                                                         const float* __restrict__ lw1,
                                                         const float* __restrict__ lw2,
                                                         u16* __restrict__ hi, u16* __restrict__ lo, int nm) {
  int o = blockIdx.x * 256 + threadIdx.x;
  int stride = gridDim.x * 256;
  int total = (2 * nm + 2) * 4096;
  for (; o < total; o += stride) {
    int m = o >> 12, r = o & 4095;
    int j = r & 7, lane = (r >> 3) & 63, nt = (r >> 9) & 3, kt = (r >> 11) & 1;
    int k = kt * 32 + ((lane >> 4) << 3) + j;
    int n = nt * 16 + (lane & 15);
    const float* src;
    if (m < nm) src = mw1 + (size_t)m * 4096;
    else if (m < 2 * nm) src = mw2 + (size_t)(m - nm) * 4096;
    else if (m == 2 * nm) src = lw1;
    else src = lw2;
    float x = src[k * 64 + n];
    u16 h = bf16_rne(x);
    hi[o] = h;
    lo[o] = bf16_rne(x - bf16_f32(h));
  }
}

// fp32 -> fp16 state init, both buffers in one dispatch (e1b|e2b contiguous)
__global__ __launch_bounds__(256) void cvtcopy2_kernel(const float* __restrict__ s1,
                                                       const float* __restrict__ s2,
                                                       f16* __restrict__ dst, int n81, int n8tot) {
  int i = blockIdx.x * 256 + threadIdx.x;
  int stride = gridDim.x * 256;
  f16x8* d8 = (f16x8*)dst;
  for (; i < n8tot; i += stride) {
    const f32x4* s4 = (i < n81) ? ((const f32x4*)s1 + 2 * (size_t)i)
                                : ((const f32x4*)s2 + 2 * (size_t)(i - n81));
    f32x4 a = s4[0], b = s4[1];
    f16x8 o;
#pragma unroll
    for (int j = 0; j < 4; j++) { o[j] = (f16)a[j]; o[4 + j] = (f16)b[j]; }
    d8[i] = o;
  }
}

__global__ __launch_bounds__(256) void relu16_kernel(f16* __restrict__ e, int n8) {
  int i = blockIdx.x * 256 + threadIdx.x;
  int stride = gridDim.x * 256;
  f16x8* e8 = (f16x8*)e;
  for (; i < n8; i += stride) {
    f16x8 v = e8[i];
#pragma unroll
    for (int j = 0; j < 8; j++) v[j] = v[j] > (f16)0 ? v[j] : (f16)0;
    e8[i] = v;
  }
}

// e[r] += B[r] + B[inv[r]]  (+ optional relu); e,B fp16
template <bool DO_RELU>
__global__ __launch_bounds__(256) void addinvB_kernel(f16* __restrict__ e, const f16* __restrict__ B,
                                                      const int* __restrict__ inv, int E) {
  int i = blockIdx.x * 256 + threadIdx.x;
  int stride = gridDim.x * 256;
  int total = E * 8;
  f16x8* e8 = (f16x8*)e;
  const f16x8* B8 = (const f16x8*)B;
  for (; i < total; i += stride) {
    int r = i >> 3, q = i & 7;
    int ir = inv[r];
    f16x8 ev = e8[i];
    f16x8 bv = B8[i];
    f16x8 biv = B8[(size_t)ir * 8 + q];
#pragma unroll
    for (int j = 0; j < 8; j++) {
      float x = (float)ev[j] + (float)bv[j] + (float)biv[j];
      ev[j] = (f16)(DO_RELU ? fmaxf(x, 0.0f) : x);
    }
    e8[i] = ev;
  }
}

// Three fused segment-sums, packed-fp16 atomics (at the ~293G dword/s + ~2.3TB/s
// random-gather joint ceiling - proven floor for this phase).
__global__ __launch_bounds__(256) void seg3_kernel(
    __half2* __restrict__ dstA, __half2* __restrict__ dstB,
    const __half2* __restrict__ paA, const __half2* __restrict__ pbA,
    const int* __restrict__ iA0, const int* __restrict__ iA1, const int* __restrict__ iA2,
    const __half2* __restrict__ paB, const __half2* __restrict__ pbB,
    const int* __restrict__ iB0, const int* __restrict__ iB1, const int* __restrict__ iB2,
    const __half2* __restrict__ paC, const __half2* __restrict__ pbC,
    const int* __restrict__ iC0, const int* __restrict__ iC1, const int* __restrict__ iC2,
    int T) {
  int i = blockIdx.x * 256 + threadIdx.x;
  int stride = gridDim.x * 256;
  int total = 3 * T * 32;
  for (; i < total; i += stride) {
    int u = i >> 5, cp = i & 31;
    __half2* dst;
    const __half2 *pa, *pb;
    const int *i0, *i1, *i2;
    int t;
    if (u < T) { t = u; dst = dstA; pa = paA; pb = pbA; i0 = iA0; i1 = iA1; i2 = iA2; }
    else if (u < 2 * T) { t = u - T; dst = dstB; pa = paB; pb = pbB; i0 = iB0; i1 = iB1; i2 = iB2; }
    else { t = u - 2 * T; dst = dstA; pa = paC; pb = pbC; i0 = iC0; i1 = iC1; i2 = iC2; }
    __half2 va = pa[(size_t)i1[t] * 32 + cp];
    __half2 vb = pb[(size_t)i2[t] * 32 + cp];
    float2 fa = __half22float2(va), fb = __half22float2(vb);
    __half2 prod = __floats2half2_rn(fa.x * fb.x, fa.y * fb.y);
    unsafeAtomicAdd(&dst[(size_t)i0[t] * 32 + cp], prod);
  }
}

// Multi-unit fused 2-layer MLP, grid-stride; fp16 state in/out; weights in VGPRs.
__global__ __launch_bounds__(256) void mlpN_kernel(
    const f16* __restrict__ e1s, const f16* __restrict__ e2s,
    f16* __restrict__ d0, f16* __restrict__ d1, f16* __restrict__ d2,
    f16* __restrict__ d3, f16* __restrict__ d4, f16* __restrict__ d5,
    const u16* __restrict__ w1h_, const u16* __restrict__ w1l_,
    const u16* __restrict__ w2h_, const u16* __restrict__ w2l_,
    const float* __restrict__ b1_, const float* __restrict__ b2_,
    int miPacked, int selMask, int nUnits, int s1, int s2, int BPU) {
  __shared__ float hshm[4][1024];
  const int u = blockIdx.x / BPU;
  if (u >= nUnits) return;
  const int tid = threadIdx.x;
  const int wave = tid >> 6, lane = tid & 63;
  const int lrow = lane & 15, lk = lane >> 4;

  const int mi = (miPacked >> (4 * u)) & 15;
  const int sel = (selMask >> u) & 1;
  const f16* src = sel ? e2s : e1s;
  const int strips = sel ? s2 : s1;
  f16* dst = (u == 0) ? d0 : (u == 1) ? d1 : (u == 2) ? d2 : (u == 3) ? d3 : (u == 4) ? d4 : d5;

  const s16x8* W1H = (const s16x8*)(w1h_ + (size_t)mi * 4096);
  const s16x8* W1L = (const s16x8*)(w1l_ + (size_t)mi * 4096);
  const s16x8* W2H = (const s16x8*)(w2h_ + (size_t)mi * 4096);
  const s16x8* W2L = (const s16x8*)(w2l_ + (size_t)mi * 4096);
  s16x8 w1h[2][4], w1l[2][4], w2h[2][4], w2l[2][4];
#pragma unroll
  for (int kt = 0; kt < 2; kt++)
#pragma unroll
    for (int nt = 0; nt < 4; nt++) {
      const int f = (kt * 4 + nt) * 64 + lane;
      w1h[kt][nt] = W1H[f];
      w1l[kt][nt] = W1L[f];
      w2h[kt][nt] = W2H[f];
      w2l[kt][nt] = W2L[f];
    }
  float bias1[4], bias2[4];
#pragma unroll
  for (int nt = 0; nt < 4; nt++) {
    bias1[nt] = b1_[mi * 64 + nt * 16 + lrow];
    bias2[nt] = b2_[mi * 64 + nt * 16 + lrow];
  }

  float* hl = hshm[wave];
  const int lb = blockIdx.x % BPU;
  for (int strip = lb * 4 + wave; strip < strips; strip += BPU * 4) {
    const f16* xp = src + (size_t)(strip * 16 + lrow) * 64 + lk * 8;
    f16x8 xa = *(const f16x8*)(xp);
    f16x8 xb = *(const f16x8*)(xp + 32);
    s16x8 ah[2], al[2];
    cvt_hilo8_f16(xa, ah[0], al[0]);
    cvt_hilo8_f16(xb, ah[1], al[1]);

    f32x4 acc[4];
#pragma unroll
    for (int nt = 0; nt < 4; nt++) { acc[nt][0] = bias1[nt]; acc[nt][1] = bias1[nt]; acc[nt][2] = bias1[nt]; acc[nt][3] = bias1[nt]; }
#pragma unroll
    for (int kt = 0; kt < 2; kt++)
#pragma unroll
      for (int nt = 0; nt < 4; nt++) {
        acc[nt] = MFMA16(ah[kt], w1h[kt][nt], acc[nt]);
        acc[nt] = MFMA16(ah[kt], w1l[kt][nt], acc[nt]);
        acc[nt] = MFMA16(al[kt], w1h[kt][nt], acc[nt]);
      }

#pragma unroll
    for (int nt = 0; nt < 4; nt++)
#pragma unroll
      for (int r = 0; r < 4; r++) {
        const int row = lk * 4 + r;
        const int col = nt * 16 + lrow;
        hl[row * 64 + (col ^ ((row & 7) << 2))] = fmaxf(acc[nt][r], 0.0f);
      }
    s16x8 bh[2], bl[2];
#pragma unroll
    for (int kt = 0; kt < 2; kt++) {
      const int colb = kt * 32 + lk * 8;
      const int xr = (lrow & 7) << 2;
      f32x4 h0 = *(const f32x4*)&hl[lrow * 64 + ((colb + 0) ^ xr)];
      f32x4 h1 = *(const f32x4*)&hl[lrow * 64 + ((colb + 4) ^ xr)];
      s16x8 hi, lo;
#pragma unroll
      for (int j = 0; j < 4; j++) {
        float x = h0[j];
        u16 hh = bf16_rne(x);
        hi[j] = (short)hh; lo[j] = (short)bf16_rne(x - bf16_f32(hh));
      }
#pragma unroll
      for (int j = 0; j < 4; j++) {
        float x = h1[j];
        u16 hh = bf16_rne(x);
        hi[4 + j] = (short)hh; lo[4 + j] = (short)bf16_rne(x - bf16_f32(hh));
      }
      bh[kt] = hi; bl[kt] = lo;
    }

    f32x4 out[4];
#pragma unroll
    for (int nt = 0; nt < 4; nt++) { out[nt][0] = bias2[nt]; out[nt][1] = bias2[nt]; out[nt][2] = bias2[nt]; out[nt][3] = bias2[nt]; }
#pragma unroll
    for (int kt = 0; kt < 2; kt++)
#pragma unroll
      for (int nt = 0; nt < 4; nt++) {
        out[nt] = MFMA16(bh[kt], w2h[kt][nt], out[nt]);
        out[nt] = MFMA16(bh[kt], w2l[kt][nt], out[nt]);
        out[nt] = MFMA16(bl[kt], w2h[kt][nt], out[nt]);
      }

    f16* dp = dst + (size_t)strip * 1024;
#pragma unroll
    for (int nt = 0; nt < 4; nt++)
#pragma unroll
      for (int r = 0; r < 4; r++)
        dp[(lk * 4 + r) * 64 + nt * 16 + lrow] = (f16)out[nt][r];
  }
}

// Both final linears in ONE dispatch. Unit 0: relu(e1)@lw1+lb1 -> dst1;
// unit 1: e2@lw2+lb2 -> dst2. Weights at wh_/wl_ + u*4096.
__global__ __launch_bounds__(256) void lin2_kernel(const f16* __restrict__ src1, const f16* __restrict__ src2,
                                                   float* __restrict__ dst1, float* __restrict__ dst2,
                                                   const u16* __restrict__ wh_, const u16* __restrict__ wl_,
                                                   const float* __restrict__ b1, const float* __restrict__ b2,
                                                   int s1, int s2, int BPL) {
  const int u = blockIdx.x / BPL;
  const int lb = blockIdx.x % BPL;
  const f16* src = u ? src2 : src1;
  float* dst = u ? dst2 : dst1;
  const float* b_ = u ? b2 : b1;
  const int strips = u ? s2 : s1;
  const bool doRelu = (u == 0);

  const int tid = threadIdx.x;
  const int wave = tid >> 6, lane = tid & 63;
  const int lrow = lane & 15, lk = lane >> 4;

  const s16x8* WH = (const s16x8*)(wh_ + (size_t)u * 4096);
  const s16x8* WL = (const s16x8*)(wl_ + (size_t)u * 4096);
  s16x8 wh[2][4], wl[2][4];
#pragma unroll
  for (int kt = 0; kt < 2; kt++)
#pragma unroll
    for (int nt = 0; nt < 4; nt++) {
      const int f = (kt * 4 + nt) * 64 + lane;
      wh[kt][nt] = WH[f];
      wl[kt][nt] = WL[f];
    }
  float bias[4];
#pragma unroll
  for (int nt = 0; nt < 4; nt++) bias[nt] = b_[nt * 16 + lrow];

  for (int s = lb * 4 + wave; s < strips; s += BPL * 4) {
    const f16* xp = src + (size_t)(s * 16 + lrow) * 64 + lk * 8;
    f16x8 xa = *(const f16x8*)(xp);
    f16x8 xb = *(const f16x8*)(xp + 32);
    if (doRelu) {
#pragma unroll
      for (int j = 0; j < 8; j++) {
        xa[j] = xa[j] > (f16)0 ? xa[j] : (f16)0;
        xb[j] = xb[j] > (f16)0 ? xb[j] : (f16)0;
      }
    }
    s16x8 ah[2], al[2];
    cvt_hilo8_f16(xa, ah[0], al[0]);
    cvt_hilo8_f16(xb, ah[1], al[1]);

    f32x4 acc[4];
#pragma unroll
    for (int nt = 0; nt < 4; nt++) { acc[nt][0] = bias[nt]; acc[nt][1] = bias[nt]; acc[nt][2] = bias[nt]; acc[nt][3] = bias[nt]; }
#pragma unroll
    for (int kt = 0; kt < 2; kt++)
#pragma unroll
      for (int nt = 0; nt < 4; nt++) {
        acc[nt] = MFMA16(ah[kt], wh[kt][nt], acc[nt]);
        acc[nt] = MFMA16(ah[kt], wl[kt][nt], acc[nt]);
        acc[nt] = MFMA16(al[kt], wh[kt][nt], acc[nt]);
      }
    float* dp = dst + (size_t)s * 1024;
#pragma unroll
    for (int nt = 0; nt < 4; nt++)
#pragma unroll
      for (int r = 0; r < 4; r++)
        dp[(lk * 4 + r) * 64 + nt * 16 + lrow] = acc[nt][r];
  }
}

extern "C" void kernel_launch(void* const* d_in, const int* in_sizes, int n_in,
                              void* d_out, int out_size, void* d_ws, size_t ws_size,
                              hipStream_t stream) {
  const float* in_e1 = (const float*)d_in[0];
  const float* in_e2 = (const float*)d_in[1];
  const int* t111 = (const int*)d_in[2];
  const int* t112 = (const int*)d_in[3];
  const int* t122 = (const int*)d_in[4];
  const int* t222 = (const int*)d_in[5];
  const int* inv1 = (const int*)d_in[6];
  const int* inv2 = (const int*)d_in[7];
  const float* mw1 = (const float*)d_in[8];
  const float* mb1 = (const float*)d_in[9];
  const float* mw2 = (const float*)d_in[10];
  const float* mb2 = (const float*)d_in[11];
  const float* lw1 = (const float*)d_in[12];
  const float* lb1 = (const float*)d_in[13];
  const float* lw2 = (const float*)d_in[14];
  const float* lb2 = (const float*)d_in[15];

  const int E1 = in_sizes[0] / 64, E2 = in_sizes[1] / 64;
  const int T = in_sizes[2] / 3;
  const int L = in_sizes[8] / (8 * 64 * 64);
  const size_t nE1 = (size_t)E1 * 64, nE2 = (size_t)E2 * 64;
  const size_t nMax = nE1 > nE2 ? nE1 : nE2;

  // ws: e1b,e2b (contiguous), mB, q0, q1 fp16 | unified weight hi|lo (bf16 fragment-ordered)
  f16* e1b = (f16*)d_ws;
  f16* e2b = e1b + nE1;
  f16* mB = e2b + nE2;
  f16* q0 = mB + nMax;
  f16* q1 = q0 + nE1;
  const size_t wmat = (size_t)L * 8 * 4096;      // elements per W1 (or W2) bank
  const size_t wtot = 2 * wmat + 8192;           // W1 | W2 | lin1 | lin2
  u16* whi = (u16*)(q1 + nE1);
  u16* wlo = whi + wtot;
  const size_t needB = (nE1 + nE2 + nMax + 2 * nE1) * 2 + 2 * wtot * 2 + 64;
  if (ws_size < needB) return;

  // q2,q3,q6,q7 (fp16, E2-sized) live in d_out; dead before lin2 writes it
  f16* q2 = (f16*)d_out;
  f16* q3 = q2 + nE2;
  f16* q6 = q3 + nE2;
  f16* q7 = q6 + nE2;
  f16* q4 = q0;  // alias: q0/q1 dead after phase-1 seg
  f16* q5 = q1;

  const int s1 = E1 / 16, s2 = E2 / 16;
  const int SEGB = 2048, ELTB = 2048, BPU = 256, BPL = 256;

  repack_all_kernel<<<256, 256, 0, stream>>>(mw1, mw2, lw1, lw2, whi, wlo, L * 8);
  cvtcopy2_kernel<<<ELTB, 256, 0, stream>>>(in_e1, in_e2, e1b, (int)(nE1 / 8), (int)((nE1 + nE2) / 8));

  for (int li = 0; li < L; li++) {
    const u16* W1H = whi + (size_t)li * 8 * 4096;
    const u16* W1L = wlo + (size_t)li * 8 * 4096;
    const u16* W2H = whi + wmat + (size_t)li * 8 * 4096;
    const u16* W2L = wlo + wmat + (size_t)li * 8 * 4096;
    const float* B1 = mb1 + (size_t)li * 8 * 64;
    const float* B2 = mb2 + (size_t)li * 8 * 64;

    // M6: q0=mlp0(e1) q1=mlp1(e1) q2=mlp2(e2) q3=mlp3(e2) q6=mlp6(e2) q7=mlp7(e2)
    mlpN_kernel<<<6 * BPU, 256, 0, stream>>>(e1b, e2b, q0, q1, q2, q3, q6, q7,
                                             W1H, W1L, W2H, W2L, B1, B2,
                                             0x763210, 0x3C, 6, s1, s2, BPU);
    hipMemsetAsync(mB, 0, nE1 * 2, stream);
    // phase 1: A=m111 (q0*q0 -> e1b), B=m112 (q1*q2 -> mB, gets inv-add), C=m122 (q3*q3 -> e1b)
    seg3_kernel<<<SEGB, 256, 0, stream>>>(
        (__half2*)e1b, (__half2*)mB,
        (const __half2*)q0, (const __half2*)q0, t111, t111 + T, t111 + 2 * T,
        (const __half2*)q1, (const __half2*)q2, t112, t112 + T, t112 + 2 * T,
        (const __half2*)q3, (const __half2*)q3, t122, t122 + T, t122 + 2 * T, T);
    addinvB_kernel<false><<<ELTB, 256, 0, stream>>>(e1b, mB, inv1, E1);

    // M2: q4=mlp4(e1_new) q5=mlp5(e1_new)  (e1 pre-relu, per reference)
    mlpN_kernel<<<2 * BPU, 256, 0, stream>>>(e1b, e2b, q4, q5, q2, q3, q6, q7,
                                             W1H, W1L, W2H, W2L, B1, B2,
                                             0x54, 0x0, 2, s1, s2, BPU);
    if (li < L - 1) relu16_kernel<<<ELTB, 256, 0, stream>>>(e1b, (int)(nE1 / 8));

    hipMemsetAsync(mB, 0, nE2 * 2, stream);
    // phase 2: A=m211 (q4*q4 -> e2b), B=m212 (q5*q6 -> mB, gets inv-add), C=m222 (q7*q7 -> e2b)
    seg3_kernel<<<SEGB, 256, 0, stream>>>(
        (__half2*)e2b, (__half2*)mB,
        (const __half2*)q4, (const __half2*)q4, t112 + 2 * T, t112, t112 + T,
        (const __half2*)q5, (const __half2*)q6, t122 + T, t122, t122 + 2 * T,
        (const __half2*)q7, (const __half2*)q7, t222, t222 + T, t222 + 2 * T, T);
    addinvB_kernel<true><<<ELTB, 256, 0, stream>>>(e2b, mB, inv2, E2);  // + relu(e2)
  }

  // both final linears, one dispatch (unit 0: relu(e1)@lw1; unit 1: e2@lw2)
  lin2_kernel<<<2 * BPL, 256, 0, stream>>>(e1b, e2b, (float*)d_out, (float*)d_out + nE1,
                                           whi + 2 * wmat, wlo + 2 * wmat, lb1, lb2, s1, s2, BPL);
}